// Round 7
// baseline (94.974 us; speedup 1.0000x reference)
//
#include <hip/hip_runtime.h>
#include <hip/hip_bf16.h>

#define NN 1024
#define DD 128
#define KK 16
#define CAP 256

typedef __attribute__((ext_vector_type(4))) float f32x4;

static __device__ __forceinline__ unsigned short f2bf(float x) {
  union { __hip_bfloat16 h; unsigned short u; } v;
  v.h = __float2bfloat16(x);
  return v.u;
}
static __device__ __forceinline__ float bf2f(unsigned short u) {
  union { unsigned int ui; float f; } v;
  v.ui = ((unsigned int)u) << 16;
  return v.f;
}

// ---------------------------------------------------------------------------
// Kernel 1: neighbor-list build (deterministic wave scan, one wave per node)
// + per-edge RBF*fcut values in f32 (e[i][s][16]).
// Tail blocks (b >= 256): straight casts embed->hb16A, w1->w1b, w2->w2b.
// ---------------------------------------------------------------------------
__global__ __launch_bounds__(256) void edge_build(
    const float* __restrict__ r, const float* __restrict__ embed,
    const float* __restrict__ w1, const float* __restrict__ w2,
    int* __restrict__ cnt, int* __restrict__ nidx, float* __restrict__ edata,
    unsigned short* __restrict__ hb16, unsigned short* __restrict__ w1b,
    unsigned short* __restrict__ w2b)
{
  int b = blockIdx.x, tid = threadIdx.x;
  if (b < 256) {
    __shared__ float Rs[NN][3];
    for (int idx = tid; idx < NN * 3; idx += 256) ((float*)Rs)[idx] = r[idx];
    __syncthreads();
    int wv = tid >> 6, lane = tid & 63;
    int i = b * 4 + wv;
    float xi = Rs[i][0], yi = Rs[i][1], zi = Rs[i][2];
    int base = 0;
    for (int it = 0; it < 16; ++it) {
      int j = it * 64 + lane;
      float dx = xi - Rs[j][0], dy = yi - Rs[j][1], dz = zi - Rs[j][2];
      float d2 = dx * dx + dy * dy + dz * dz;
      bool on = (j != i) && (d2 < 4.0f);
      unsigned long long mask = __ballot(on);
      int slot = base + (int)__popcll(mask & ((1ull << lane) - 1ull));
      if (on && slot < CAP) {
        float dist = sqrtf(d2);
        float w  = 0.5f * (__cosf(1.57079632679f * dist) + 1.0f);  // cos(pi*d/2)
        float E0 = __expf(-10.0f * d2);
        float q  = __expf(2.66666667f * dist);      // exp(20*(2/15)*d)
        float u  = __expf(-0.17777778f);            // exp(-10*(2/15)^2)
        float u2 = u * u;
        float p = 1.0f, c = 1.0f, s = u;
        float vals[KK];
        #pragma unroll
        for (int k = 0; k < KK; ++k) {
          vals[k] = w * (E0 * p) * c;   // = w * exp(-10*(dist - k*2/15)^2)
          p *= q; c *= s; s *= u2;
        }
        nidx[i * CAP + slot] = j;
        float* dst = edata + ((size_t)i * CAP + slot) * KK;
        #pragma unroll
        for (int k = 0; k < KK; ++k) dst[k] = vals[k];
      }
      base += (int)__popcll(mask);
    }
    if (lane == 0) cnt[i] = (base < CAP) ? base : CAP;
  } else {
    // straight casts: embed (131072) | w1 (49152) | w2 (49152)
    int gt = (b - 256) * 256 + tid;
    for (int f = gt; f < 229376; f += 4096) {
      if (f < 131072)      hb16[f]          = f2bf(embed[f]);
      else if (f < 180224) w1b[f - 131072]  = f2bf(w1[f - 131072]);
      else                 w2b[f - 180224]  = f2bf(w2[f - 180224]);
    }
  }
}

// ---------------------------------------------------------------------------
// Kernel 2 (per layer): fused sparse aggregation + node MLP. One WG per node.
// Thread t: d = t&127, p = t>>7; halves split the neighbor list (s = p mod 2).
// agg[d] = sum_s (sum_k e[s,k]*wf[k,d]) * h_bf16[j_s, d]    (all f32 math)
// then MLP: silu(x@w1+b1)@w2+b2 + residual, VALU dot-products.
// ---------------------------------------------------------------------------
__global__ __launch_bounds__(256) void layer_fused(
    const int* __restrict__ cnt, const int* __restrict__ nidx,
    const float* __restrict__ edata,
    const unsigned short* __restrict__ hb16in,
    const float* __restrict__ hprev,
    const float* __restrict__ wf,                 // [16][128] layer slice
    const unsigned short* __restrict__ w1b, const float* __restrict__ b1,
    const unsigned short* __restrict__ w2b, const float* __restrict__ b2,
    float* __restrict__ hnext,                    // f32 out (non-final)
    unsigned short* __restrict__ hb16out,         // bf16 out (non-final)
    float* __restrict__ outf)                     // d_out (final)
{
  __shared__ float part[2][128];
  __shared__ float xv[128];
  __shared__ float yv[128];
  int i = blockIdx.x, tid = threadIdx.x;
  int d = tid & 127, p = tid >> 7;

  float wfv[KK];
  #pragma unroll
  for (int k = 0; k < KK; ++k) wfv[k] = wf[k * DD + d];

  int cn = cnt[i];
  const int* nx = nidx + i * CAP;
  float aggp = 0.f;
  #pragma unroll 2
  for (int s = p; s < cn; s += 2) {
    int j = nx[s];
    const float* ep = edata + ((size_t)i * CAP + s) * KK;
    float F = 0.f;
    #pragma unroll
    for (int k = 0; k < KK; ++k) F += ep[k] * wfv[k];
    aggp += F * bf2f(hb16in[j * DD + d]);
  }
  part[p][d] = aggp;
  __syncthreads();
  if (tid < 128) xv[d] = part[0][d] + part[1][d];
  __syncthreads();

  // GEMM1: o1[d] partial over input dims p*64..p*64+63
  float o1 = 0.f;
  #pragma unroll 4
  for (int dd = 0; dd < 64; ++dd) {
    int di = p * 64 + dd;
    o1 += xv[di] * bf2f(w1b[di * DD + d]);
  }
  part[p][d] = o1;
  __syncthreads();
  if (tid < 128) {
    float x = part[0][d] + part[1][d] + b1[d];
    yv[d] = x / (1.f + __expf(-x));     // silu
  }
  __syncthreads();

  // GEMM2
  float o2 = 0.f;
  #pragma unroll 4
  for (int dd = 0; dd < 64; ++dd) {
    int di = p * 64 + dd;
    o2 += yv[di] * bf2f(w2b[di * DD + d]);
  }
  part[p][d] = o2;
  __syncthreads();
  if (tid < 128) {
    float v = part[0][d] + part[1][d] + b2[d] + hprev[(size_t)i * DD + d];
    if (outf) {
      outf[(size_t)i * DD + d] = v;
    } else {
      hnext[(size_t)i * DD + d]   = v;
      hb16out[(size_t)i * DD + d] = f2bf(v);
    }
  }
}

// ---------------------------------------------------------------------------
extern "C" void kernel_launch(void* const* d_in, const int* in_sizes, int n_in,
                              void* d_out, int out_size, void* d_ws, size_t ws_size,
                              hipStream_t stream) {
  (void)in_sizes; (void)n_in; (void)out_size; (void)ws_size;
  const float* r     = (const float*)d_in[0];
  const float* embed = (const float*)d_in[1];
  const float* wfilt = (const float*)d_in[2];
  const float* w1    = (const float*)d_in[3];
  const float* b1    = (const float*)d_in[4];
  const float* w2    = (const float*)d_in[5];
  const float* b2    = (const float*)d_in[6];

  char* ws = (char*)d_ws;
  size_t off = 0;
  auto alloc = [&](size_t bytes) {
    void* p = ws + off; off += (bytes + 255) & ~(size_t)255; return p;
  };
  float*          EDATA = (float*)alloc((size_t)NN * CAP * KK * 4);   // 16.8 MB
  int*            NIDX  = (int*)alloc((size_t)NN * CAP * 4);          // 1 MB
  int*            CNT   = (int*)alloc((size_t)NN * 4);
  unsigned short* HB16A = (unsigned short*)alloc((size_t)NN * DD * 2);
  unsigned short* HB16B = (unsigned short*)alloc((size_t)NN * DD * 2);
  unsigned short* W1B   = (unsigned short*)alloc((size_t)3 * DD * DD * 2);
  unsigned short* W2B   = (unsigned short*)alloc((size_t)3 * DD * DD * 2);
  float*          HB    = (float*)alloc((size_t)NN * DD * 4);

  edge_build<<<272, 256, 0, stream>>>(r, embed, w1, w2,
                                      CNT, NIDX, EDATA, HB16A, W1B, W2B);

  const float* hp = embed;
  for (int l = 0; l < 3; ++l) {
    bool fin = (l == 2);
    const unsigned short* in16  = (l == 1) ? HB16B : HB16A;
    unsigned short*       out16 = (l == 0) ? HB16B : HB16A;
    layer_fused<<<NN, 256, 0, stream>>>(
        CNT, NIDX, EDATA, in16, hp,
        wfilt + (size_t)l * KK * DD,
        W1B + (size_t)l * DD * DD, b1 + (size_t)l * DD,
        W2B + (size_t)l * DD * DD, b2 + (size_t)l * DD,
        fin ? nullptr : HB, fin ? nullptr : out16,
        fin ? (float*)d_out : nullptr);
    hp = HB;
  }
}

// Round 8
// 45.008 us; speedup vs baseline: 2.1102x; 2.1102x over previous
//
#include <hip/hip_runtime.h>
#include <hip/hip_bf16.h>

#define NN 1024
#define DD 128
#define KK 16
#define CAP 128

typedef __attribute__((ext_vector_type(4))) float f32x4;
typedef __attribute__((ext_vector_type(8))) short bf16x8;
typedef __attribute__((ext_vector_type(4))) unsigned int u32x4;

static __device__ __forceinline__ unsigned short f2bf(float x) {
  union { __hip_bfloat16 h; unsigned short u; } v;
  v.h = __float2bfloat16(x);
  return v.u;
}
static __device__ __forceinline__ float bf2f(unsigned short u) {
  union { unsigned int ui; float f; } v;
  v.ui = ((unsigned int)u) << 16;
  return v.f;
}

// ---------------------------------------------------------------------------
// Kernel 1: neighbor lists (wave ballot scan) + per-edge RBF in bf16.
// Tail: casts embed/w1/w2 -> bf16; block 272 builds wfT[3][128][32] (k-padded).
// ---------------------------------------------------------------------------
__global__ __launch_bounds__(256) void edge_build(
    const float* __restrict__ r, const float* __restrict__ embed,
    const float* __restrict__ w1, const float* __restrict__ w2,
    const float* __restrict__ wfilt,
    int* __restrict__ cnt, int* __restrict__ nidx,
    unsigned short* __restrict__ edata16,
    unsigned short* __restrict__ hb16, unsigned short* __restrict__ w1b,
    unsigned short* __restrict__ w2b, unsigned short* __restrict__ wfT)
{
  int b = blockIdx.x, tid = threadIdx.x;
  if (b < 256) {
    __shared__ float Rs[NN][3];
    for (int idx = tid; idx < NN * 3; idx += 256) ((float*)Rs)[idx] = r[idx];
    __syncthreads();
    int wv = tid >> 6, lane = tid & 63;
    int i = b * 4 + wv;
    float xi = Rs[i][0], yi = Rs[i][1], zi = Rs[i][2];
    int base = 0;
    for (int it = 0; it < 16; ++it) {
      int j = it * 64 + lane;
      float dx = xi - Rs[j][0], dy = yi - Rs[j][1], dz = zi - Rs[j][2];
      float d2 = dx * dx + dy * dy + dz * dz;
      bool on = (j != i) && (d2 < 4.0f);
      unsigned long long mask = __ballot(on);
      int slot = base + (int)__popcll(mask & ((1ull << lane) - 1ull));
      if (on && slot < CAP) {
        float dist = sqrtf(d2);
        float w  = 0.5f * (__cosf(1.57079632679f * dist) + 1.0f);  // cos(pi*d/2)
        float E0 = __expf(-10.0f * d2);
        float q  = __expf(2.66666667f * dist);      // exp(20*(2/15)*d)
        float u  = __expf(-0.17777778f);            // exp(-10*(2/15)^2)
        float u2 = u * u;
        float p = 1.0f, c = 1.0f, s = u;
        float vals[KK];
        #pragma unroll
        for (int k = 0; k < KK; ++k) {
          vals[k] = w * (E0 * p) * c;   // = w * exp(-10*(dist - k*2/15)^2)
          p *= q; c *= s; s *= u2;
        }
        nidx[i * CAP + slot] = j;
        unsigned short* dst = edata16 + ((size_t)i * CAP + slot) * KK;
        #pragma unroll
        for (int k = 0; k < KK; ++k) dst[k] = f2bf(vals[k]);
      }
      base += (int)__popcll(mask);
    }
    if (lane == 0) cnt[i] = (base < CAP) ? base : CAP;
  } else if (b < 272) {
    // straight casts: embed (131072) | w1 (49152) | w2 (49152)
    int gt = (b - 256) * 256 + tid;
    for (int f = gt; f < 229376; f += 4096) {
      if (f < 131072)      hb16[f]          = f2bf(embed[f]);
      else if (f < 180224) w1b[f - 131072]  = f2bf(w1[f - 131072]);
      else                 w2b[f - 180224]  = f2bf(w2[f - 180224]);
    }
  } else {
    // wfT[l][d][kk]: transpose of wfilt[l][k][d], k zero-padded 16->32
    for (int e = tid; e < 3 * 128 * 32; e += 256) {
      int l = e >> 12, rem = e & 4095, dd = rem >> 5, kk = rem & 31;
      wfT[e] = (kk < KK) ? f2bf(wfilt[l * 2048 + kk * 128 + dd])
                         : (unsigned short)0;
    }
  }
}

// ---------------------------------------------------------------------------
// Kernel 2 (per layer): one WG per node. Panels of 64 edges:
//   stage Hs (neighbor h rows, bf16) + As (edge RBF, k-padded) in LDS,
//   F = e @ wfT via mfma_f32_16x16x32_bf16 (r2-verified fragment layout),
//   PV: agg_d += F[s][d] * Hs[s][d], shfl row-reduce.
// Then node MLP (VALU, bf16-pair loads, 4-way di split) + residual.
// ---------------------------------------------------------------------------
__global__ __launch_bounds__(256) void layer_fused(
    const int* __restrict__ cnt, const int* __restrict__ nidx,
    const unsigned short* __restrict__ edata16,
    const unsigned short* __restrict__ hb16in,
    const float* __restrict__ hprev,
    const unsigned short* __restrict__ wfTL,      // [128][32] bf16 this layer
    const unsigned short* __restrict__ w1b, const float* __restrict__ b1,
    const unsigned short* __restrict__ w2b, const float* __restrict__ b2,
    float* __restrict__ hnext,
    unsigned short* __restrict__ hb16out,
    float* __restrict__ outf)
{
  __shared__ unsigned short Hs[64][136];   // neighbor h rows (272B stride, 16B-aligned)
  __shared__ unsigned short As[64][40];    // edge RBF rows, k in [0,32) zero-padded
  __shared__ float xv[128];
  __shared__ float yv[128];
  __shared__ float part4[4][128];

  int i = blockIdx.x, tid = threadIdx.x;
  int w = tid >> 6, lane = tid & 63;
  int lg = lane >> 4, l16 = lane & 15;
  int cn = cnt[i];
  const int* nx = nidx + i * CAP;

  // B fragments (layer-constant): nt in {0,1}, N-row d = (w*2+nt)*16 + l16
  bf16x8 bfr[2];
  #pragma unroll
  for (int nt = 0; nt < 2; ++nt) {
    int d = (w * 2 + nt) * 16 + l16;
    bfr[nt] = *(const bf16x8*)(wfTL + d * 32 + lg * 8);
  }

  float aggv0 = 0.f, aggv1 = 0.f;

  for (int p64 = 0; p64 < cn; p64 += 64) {
    int local_n = cn - p64; if (local_n > 64) local_n = 64;
    __syncthreads();   // prev panel's PV reads done before restage
    // stage Hs: 64 rows x 16 dwordx4 chunks
    #pragma unroll
    for (int it = 0; it < 4; ++it) {
      int c = tid + it * 256;
      int row = c >> 4, ch = c & 15;
      u32x4 v = {0u, 0u, 0u, 0u};
      if (row < local_n) {
        int j = nx[p64 + row];
        v = *(const u32x4*)(hb16in + (size_t)j * DD + ch * 8);
      }
      *(u32x4*)(&Hs[row][ch * 8]) = v;
    }
    // stage As: 64 rows x 4 chunks (2 data + 2 zero-pad)
    {
      int row = tid >> 2, ch = tid & 3;
      u32x4 v = {0u, 0u, 0u, 0u};
      if (row < local_n && ch < 2)
        v = *(const u32x4*)(edata16 + ((size_t)i * CAP + p64 + row) * KK + ch * 8);
      *(u32x4*)(&As[row][ch * 8]) = v;
    }
    __syncthreads();

    // F = e @ wfT : acc[mt][nt], C[row=edge s][col=d]
    bf16x8 af[4];
    #pragma unroll
    for (int mt = 0; mt < 4; ++mt)
      af[mt] = *(const bf16x8*)(&As[mt * 16 + l16][lg * 8]);
    f32x4 acc[4][2];
    #pragma unroll
    for (int mt = 0; mt < 4; ++mt)
      #pragma unroll
      for (int nt = 0; nt < 2; ++nt)
        acc[mt][nt] = (f32x4){0.f, 0.f, 0.f, 0.f};
    #pragma unroll
    for (int mt = 0; mt < 4; ++mt)
      #pragma unroll
      for (int nt = 0; nt < 2; ++nt)
        acc[mt][nt] = __builtin_amdgcn_mfma_f32_16x16x32_bf16(
            af[mt], bfr[nt], acc[mt][nt], 0, 0, 0);

    // PV: agg_d += F[s][d] * h[s][d]   (s = mt*16 + lg*4 + rr)
    #pragma unroll
    for (int nt = 0; nt < 2; ++nt) {
      int d = (w * 2 + nt) * 16 + l16;
      float s = 0.f;
      #pragma unroll
      for (int mt = 0; mt < 4; ++mt)
        #pragma unroll
        for (int rr = 0; rr < 4; ++rr)
          s += acc[mt][nt][rr] * bf2f(Hs[mt * 16 + lg * 4 + rr][d]);
      if (nt == 0) aggv0 += s; else aggv1 += s;
    }
  }
  // reduce over the 4 lg row-groups
  aggv0 += __shfl_xor(aggv0, 16, 64);
  aggv0 += __shfl_xor(aggv0, 32, 64);
  aggv1 += __shfl_xor(aggv1, 16, 64);
  aggv1 += __shfl_xor(aggv1, 32, 64);
  if (lg == 0) {
    xv[(w * 2 + 0) * 16 + l16] = aggv0;
    xv[(w * 2 + 1) * 16 + l16] = aggv1;
  }
  __syncthreads();

  // ---------------- node MLP ----------------
  int dp = tid & 63, pp = tid >> 6;
  float o1a = 0.f, o1b = 0.f;
  #pragma unroll 8
  for (int q = 0; q < 32; ++q) {
    int di = pp * 32 + q;
    float x = xv[di];
    unsigned int wp = *(const unsigned int*)(w1b + di * DD + dp * 2);
    o1a += x * bf2f((unsigned short)(wp & 0xffffu));
    o1b += x * bf2f((unsigned short)(wp >> 16));
  }
  part4[pp][dp * 2] = o1a;
  part4[pp][dp * 2 + 1] = o1b;
  __syncthreads();
  if (tid < 128) {
    float x = part4[0][tid] + part4[1][tid] + part4[2][tid] + part4[3][tid] + b1[tid];
    yv[tid] = x / (1.f + __expf(-x));   // silu
  }
  __syncthreads();
  float o2a = 0.f, o2b = 0.f;
  #pragma unroll 8
  for (int q = 0; q < 32; ++q) {
    int di = pp * 32 + q;
    float yy = yv[di];
    unsigned int wp = *(const unsigned int*)(w2b + di * DD + dp * 2);
    o2a += yy * bf2f((unsigned short)(wp & 0xffffu));
    o2b += yy * bf2f((unsigned short)(wp >> 16));
  }
  part4[pp][dp * 2] = o2a;
  part4[pp][dp * 2 + 1] = o2b;
  __syncthreads();
  if (tid < 128) {
    float v = part4[0][tid] + part4[1][tid] + part4[2][tid] + part4[3][tid]
              + b2[tid] + hprev[(size_t)i * DD + tid];
    if (outf) {
      outf[(size_t)i * DD + tid] = v;
    } else {
      hnext[(size_t)i * DD + tid]   = v;
      hb16out[(size_t)i * DD + tid] = f2bf(v);
    }
  }
}

// ---------------------------------------------------------------------------
extern "C" void kernel_launch(void* const* d_in, const int* in_sizes, int n_in,
                              void* d_out, int out_size, void* d_ws, size_t ws_size,
                              hipStream_t stream) {
  (void)in_sizes; (void)n_in; (void)out_size; (void)ws_size;
  const float* r     = (const float*)d_in[0];
  const float* embed = (const float*)d_in[1];
  const float* wfilt = (const float*)d_in[2];
  const float* w1    = (const float*)d_in[3];
  const float* b1    = (const float*)d_in[4];
  const float* w2    = (const float*)d_in[5];
  const float* b2    = (const float*)d_in[6];

  char* ws = (char*)d_ws;
  size_t off = 0;
  auto alloc = [&](size_t bytes) {
    void* p = ws + off; off += (bytes + 255) & ~(size_t)255; return p;
  };
  unsigned short* EDATA = (unsigned short*)alloc((size_t)NN * CAP * KK * 2); // 4.2 MB
  int*            NIDX  = (int*)alloc((size_t)NN * CAP * 4);                 // 512 KB
  int*            CNT   = (int*)alloc((size_t)NN * 4);
  unsigned short* HB16A = (unsigned short*)alloc((size_t)NN * DD * 2);
  unsigned short* HB16B = (unsigned short*)alloc((size_t)NN * DD * 2);
  unsigned short* W1B   = (unsigned short*)alloc((size_t)3 * DD * DD * 2);
  unsigned short* W2B   = (unsigned short*)alloc((size_t)3 * DD * DD * 2);
  unsigned short* WFT   = (unsigned short*)alloc((size_t)3 * DD * 32 * 2);
  float*          HB    = (float*)alloc((size_t)NN * DD * 4);

  edge_build<<<273, 256, 0, stream>>>(r, embed, w1, w2, wfilt,
                                      CNT, NIDX, EDATA, HB16A, W1B, W2B, WFT);

  const float* hp = embed;
  for (int l = 0; l < 3; ++l) {
    bool fin = (l == 2);
    const unsigned short* in16  = (l == 1) ? HB16B : HB16A;
    unsigned short*       out16 = (l == 0) ? HB16B : HB16A;
    layer_fused<<<NN, 256, 0, stream>>>(
        CNT, NIDX, EDATA, in16, hp,
        WFT + (size_t)l * DD * 32,
        W1B + (size_t)l * DD * DD, b1 + (size_t)l * DD,
        W2B + (size_t)l * DD * DD, b2 + (size_t)l * DD,
        fin ? nullptr : HB, fin ? nullptr : out16,
        fin ? (float*)d_out : nullptr);
    hp = HB;
  }
}